// Round 1
// baseline (213.013 us; speedup 1.0000x reference)
//
#include <hip/hip_runtime.h>

// Problem constants (inputs are [32,3,512,512] f32; pooled grid 128x128)
#define HH 512
#define WW 512
#define PH 128
#define PW 128
#define CC 3

// Kernel 1: g[b,i,j] = (1/48) * sum_{c,4x4 block} (orig - enh)
// One thread per pooled pixel. 24 float4 loads/thread, fully coalesced.
__global__ void __launch_bounds__(256)
pool_diff_kernel(const float* __restrict__ orig,
                 const float* __restrict__ enh,
                 float* __restrict__ g, int total) {
    int idx = blockIdx.x * blockDim.x + threadIdx.x;
    if (idx >= total) return;
    int j = idx & (PW - 1);
    int i = (idx >> 7) & (PH - 1);
    int b = idx >> 14;

    const size_t img = (size_t)HH * WW;              // 262144
    const size_t base = (size_t)b * CC * img + (size_t)(i * 4) * WW + (size_t)(j * 4);

    float s = 0.0f;
#pragma unroll
    for (int c = 0; c < CC; ++c) {
#pragma unroll
        for (int r = 0; r < 4; ++r) {
            const size_t off = base + (size_t)c * img + (size_t)r * WW;
            const float4 o = *(const float4*)(orig + off);
            const float4 e = *(const float4*)(enh + off);
            s += (o.x - e.x) + (o.y - e.y) + (o.z - e.z) + (o.w - e.w);
        }
    }
    g[idx] = s * (1.0f / 48.0f);
}

// Kernel 2: loss[i,j] = sum over {l,r,u,d} of (g[i,j] - g_pad[neighbor])^2
// Zero padding: out-of-bounds neighbor contributes 0 (so diff = g[i,j]).
__global__ void __launch_bounds__(256)
stencil_loss_kernel(const float* __restrict__ g,
                    float* __restrict__ out, int total) {
    int idx = blockIdx.x * blockDim.x + threadIdx.x;
    if (idx >= total) return;
    int j = idx & (PW - 1);
    int i = (idx >> 7) & (PH - 1);

    float c = g[idx];
    float l = (j > 0)      ? g[idx - 1]  : 0.0f;
    float r = (j < PW - 1) ? g[idx + 1]  : 0.0f;
    float u = (i > 0)      ? g[idx - PW] : 0.0f;
    float d = (i < PH - 1) ? g[idx + PW] : 0.0f;

    float dl = c - l, dr = c - r, du = c - u, dd = c - d;
    out[idx] = dl * dl + dr * dr + du * du + dd * dd;
}

extern "C" void kernel_launch(void* const* d_in, const int* in_sizes, int n_in,
                              void* d_out, int out_size, void* d_ws, size_t ws_size,
                              hipStream_t stream) {
    const float* orig = (const float*)d_in[0];
    const float* enh  = (const float*)d_in[1];
    float* out = (float*)d_out;
    float* g   = (float*)d_ws;  // 32*128*128 floats = 2 MB scratch

    const int batch = in_sizes[0] / (CC * HH * WW);   // 32
    const int total = batch * PH * PW;                // 524288

    const int block = 256;
    const int grid = (total + block - 1) / block;     // 2048

    pool_diff_kernel<<<grid, block, 0, stream>>>(orig, enh, g, total);
    stencil_loss_kernel<<<grid, block, 0, stream>>>(g, out, total);
}

// Round 2
// 212.083 us; speedup vs baseline: 1.0044x; 1.0044x over previous
//
#include <hip/hip_runtime.h>

// Inputs: [32,3,512,512] f32; pooled grid 128x128 per image.
#define HH 512
#define WW 512
#define PH 128
#define PW 128
#define CC 3

// Kernel 1: g[b,i,j] = (1/48) * sum_{c, 4x4 block} (orig - enh)
// One thread per pooled pixel. All 24 float4 loads staged into registers
// BEFORE accumulation -> ~24 loads in flight per wave (vs ~3 at VGPR=16 in R0).
__global__ void __launch_bounds__(256)
pool_diff_kernel(const float* __restrict__ orig,
                 const float* __restrict__ enh,
                 float* __restrict__ g, int total) {
    int idx = blockIdx.x * blockDim.x + threadIdx.x;
    if (idx >= total) return;
    int j = idx & (PW - 1);
    int i = (idx >> 7) & (PH - 1);
    int b = idx >> 14;

    const size_t img = (size_t)HH * WW;              // 262144
    const size_t base = (size_t)b * CC * img + (size_t)(i * 4) * WW + (size_t)(j * 4);

    float4 ov[12], ev[12];
#pragma unroll
    for (int c = 0; c < CC; ++c) {
#pragma unroll
        for (int r = 0; r < 4; ++r) {
            const size_t off = base + (size_t)c * img + (size_t)r * WW;
            ov[c * 4 + r] = *(const float4*)(orig + off);
        }
    }
#pragma unroll
    for (int c = 0; c < CC; ++c) {
#pragma unroll
        for (int r = 0; r < 4; ++r) {
            const size_t off = base + (size_t)c * img + (size_t)r * WW;
            ev[c * 4 + r] = *(const float4*)(enh + off);
        }
    }

    float s = 0.0f;
#pragma unroll
    for (int t = 0; t < 12; ++t) {
        s += (ov[t].x - ev[t].x) + (ov[t].y - ev[t].y)
           + (ov[t].z - ev[t].z) + (ov[t].w - ev[t].w);
    }
    g[idx] = s * (1.0f / 48.0f);
}

// Kernel 2: loss[i,j] = sum over {l,r,u,d} of (g[i,j] - g_pad[neighbor])^2
// Zero padding: out-of-bounds neighbor contributes 0 (so diff = g[i,j]).
__global__ void __launch_bounds__(256)
stencil_loss_kernel(const float* __restrict__ g,
                    float* __restrict__ out, int total) {
    int idx = blockIdx.x * blockDim.x + threadIdx.x;
    if (idx >= total) return;
    int j = idx & (PW - 1);
    int i = (idx >> 7) & (PH - 1);

    float c = g[idx];
    float l = (j > 0)      ? g[idx - 1]  : 0.0f;
    float r = (j < PW - 1) ? g[idx + 1]  : 0.0f;
    float u = (i > 0)      ? g[idx - PW] : 0.0f;
    float d = (i < PH - 1) ? g[idx + PW] : 0.0f;

    float dl = c - l, dr = c - r, du = c - u, dd = c - d;
    out[idx] = dl * dl + dr * dr + du * du + dd * dd;
}

extern "C" void kernel_launch(void* const* d_in, const int* in_sizes, int n_in,
                              void* d_out, int out_size, void* d_ws, size_t ws_size,
                              hipStream_t stream) {
    const float* orig = (const float*)d_in[0];
    const float* enh  = (const float*)d_in[1];
    float* out = (float*)d_out;
    float* g   = (float*)d_ws;  // 32*128*128 floats = 2 MB scratch

    const int batch = in_sizes[0] / (CC * HH * WW);   // 32
    const int total = batch * PH * PW;                // 524288

    const int block = 256;
    const int grid = (total + block - 1) / block;     // 2048

    pool_diff_kernel<<<grid, block, 0, stream>>>(orig, enh, g, total);
    stencil_loss_kernel<<<grid, block, 0, stream>>>(g, out, total);
}

// Round 3
// 211.071 us; speedup vs baseline: 1.0092x; 1.0048x over previous
//
#include <hip/hip_runtime.h>

// Inputs: [32,3,512,512] f32; pooled grid 128x128 per image.
#define HH 512
#define WW 512
#define PH 128
#define PW 128
#define CC 3

// Kernel 1: g[b,i,j] = (1/48) * sum_{c, 4x4 block} (orig - enh)
// One block per (batch, pooled row). The 4 source rows (4i..4i+3) are
// CONTIGUOUS 8KB chunks per channel -> sequential, page-local access
// (vs R1's per-thread 2KB/1MB-strided scatter that thrashed the UTCL1).
// tid = half*128 + j: thread loads rows {2*half, 2*half+1}, cols 4j..4j+3,
// for all 3 channels; halves combined via LDS.
__global__ void __launch_bounds__(256)
pool_diff_kernel(const float* __restrict__ orig,
                 const float* __restrict__ enh,
                 float* __restrict__ g) {
    const int bi   = blockIdx.x;       // b*128 + i
    const int tid  = threadIdx.x;
    const int j    = tid & (PW - 1);   // pooled col
    const int half = tid >> 7;         // 0: rows 0-1, 1: rows 2-3

    const size_t img     = (size_t)HH * WW;                       // 262144
    const int    b       = bi >> 7;
    const int    i       = bi & (PH - 1);
    const size_t rowbase = (size_t)b * CC * img + (size_t)(4 * i) * WW;

    float s = 0.0f;
#pragma unroll
    for (int c = 0; c < CC; ++c) {
        const size_t off = rowbase + (size_t)c * img + (size_t)(2 * half) * WW + (size_t)(4 * j);
        const float4 o0 = *(const float4*)(orig + off);
        const float4 o1 = *(const float4*)(orig + off + WW);
        const float4 e0 = *(const float4*)(enh + off);
        const float4 e1 = *(const float4*)(enh + off + WW);
        s += (o0.x - e0.x) + (o0.y - e0.y) + (o0.z - e0.z) + (o0.w - e0.w)
           + (o1.x - e1.x) + (o1.y - e1.y) + (o1.z - e1.z) + (o1.w - e1.w);
    }

    __shared__ float part[2][PW];
    part[half][j] = s;
    __syncthreads();
    if (tid < PW) {
        g[(size_t)bi * PW + tid] = (part[0][tid] + part[1][tid]) * (1.0f / 48.0f);
    }
}

// Kernel 2: loss[i,j] = sum over {l,r,u,d} of (g[i,j] - g_pad[neighbor])^2
// Zero padding: out-of-bounds neighbor contributes 0 (so diff = g[i,j]).
__global__ void __launch_bounds__(256)
stencil_loss_kernel(const float* __restrict__ g,
                    float* __restrict__ out, int total) {
    int idx = blockIdx.x * blockDim.x + threadIdx.x;
    if (idx >= total) return;
    int j = idx & (PW - 1);
    int i = (idx >> 7) & (PH - 1);

    float c = g[idx];
    float l = (j > 0)      ? g[idx - 1]  : 0.0f;
    float r = (j < PW - 1) ? g[idx + 1]  : 0.0f;
    float u = (i > 0)      ? g[idx - PW] : 0.0f;
    float d = (i < PH - 1) ? g[idx + PW] : 0.0f;

    float dl = c - l, dr = c - r, du = c - u, dd = c - d;
    out[idx] = dl * dl + dr * dr + du * du + dd * dd;
}

extern "C" void kernel_launch(void* const* d_in, const int* in_sizes, int n_in,
                              void* d_out, int out_size, void* d_ws, size_t ws_size,
                              hipStream_t stream) {
    const float* orig = (const float*)d_in[0];
    const float* enh  = (const float*)d_in[1];
    float* out = (float*)d_out;
    float* g   = (float*)d_ws;  // 32*128*128 floats = 2 MB scratch

    const int batch = in_sizes[0] / (CC * HH * WW);   // 32
    const int total = batch * PH * PW;                // 524288

    pool_diff_kernel<<<batch * PH, 256, 0, stream>>>(orig, enh, g);

    const int block = 256;
    const int grid = (total + block - 1) / block;     // 2048
    stencil_loss_kernel<<<grid, block, 0, stream>>>(g, out, total);
}